// Round 1
// baseline (3717.992 us; speedup 1.0000x reference)
//
#include <hip/hip_runtime.h>
#include <math.h>

// SSL compressor gain: 128 independent nonlinear IIR chains over T=131072.
// Serial-latency-bound: 1 thread per batch row, scaled-state formulation to
// minimize the dependent chain (~20 cy) and instruction count (12 VALU/step).

struct SslParams { float nhs, hst, nq, r, a_af, a_as, a_sf, a_ss; };

__device__ __forceinline__ double dsecs(double u, double tmin, double tmax) {
    double s = 1.0 / (1.0 + exp(-u));
    return tmin + (tmax - tmin) * s;
}

__device__ __forceinline__ SslParams ssl_params(
        const float* cth, const float* rl, const float* fbl,
        const float* uaf, const float* uas, const float* usf, const float* uss) {
    const double FS = 44100.0;
    const double T_AF_MIN = 820.0 * 4.7e-07 * 0.8,   T_AF_MAX = 270000.0 * 4.7e-07 * 1.2;
    const double T_AS_MIN = 820.0 * 6.8e-06 * 0.8,   T_AS_MAX = 270000.0 * 6.8e-06 * 100.0;
    const double T_SF_MIN = 91000.0 * 4.7e-07 * 0.8, T_SF_MAX = 1200000.0 * 4.7e-07 * 1.2;
    const double T_SS_MIN = 750000.0 * 6.8e-06 * 0.8, T_SS_MAX = 750000.0 * 6.8e-06 * 100.0;

    double cr    = fmax(exp((double)rl[0]) + 1.0, 1.0 + 1e-4);
    double fb    = 1.0 / (1.0 + exp(-(double)fbl[0]));
    double slope = 1.0 - 1.0 / cr;

    SslParams p;
    p.a_af = (float)exp(-1.0 / (FS * dsecs((double)uaf[0], T_AF_MIN, T_AF_MAX)));
    p.a_as = (float)exp(-1.0 / (FS * dsecs((double)uas[0], T_AS_MIN, T_AS_MAX)));
    p.a_sf = (float)exp(-1.0 / (FS * dsecs((double)usf[0], T_SF_MIN, T_SF_MAX)));
    p.a_ss = (float)exp(-1.0 / (FS * dsecs((double)uss[0], T_SS_MIN, T_SS_MAX)));
    double q = 0.5 * slope * fb;          // feedback coupling in scaled domain
    p.nq  = (float)(-q);
    p.r   = (float)(0.5 + q);             // gate: att <=> sx2 < r*Y
    p.nhs = (float)(-0.5 * slope);        // sx2 = nhs*x + hst
    p.hst = (float)(0.5 * slope * (double)cth[0]);
    return p;
}

// Scaled-state recurrence (EF=-ef/2, ES=-es/2, Y=EF+ES=y):
//   sx2 = -0.5*slope*(x - thresh)
//   u2  = sx2 - q*Y            (= -0.5 * pre-relu target)
//   t2  = min(u2, 0)           (= -0.5 * tgt)
//   att = sx2 < r*Y            (equivalent to tgt > 0.5*(ef+es))
//   EF' = t2 + af*(EF - t2);  ES' = t2 + as*(ES - t2);  Y' = EF'+ES' = y
__global__ __launch_bounds__(64) void ssl_comp_serial(
        const float* __restrict__ x, float* __restrict__ out,
        const float* cth, const float* rl, const float* fbl,
        const float* uaf, const float* uas, const float* usf, const float* uss,
        int B, int T)
{
    int b = blockIdx.x * blockDim.x + threadIdx.x;
    if (b >= B) return;

    SslParams P = ssl_params(cth, rl, fbl, uaf, uas, usf, uss);
    const float nhs = P.nhs, hst = P.hst, nq = P.nq, r = P.r;
    const float a_af = P.a_af, a_as = P.a_as, a_sf = P.a_sf, a_ss = P.a_ss;

    const float4* __restrict__ xr = reinterpret_cast<const float4*>(x + (size_t)b * T);
    float4* __restrict__ yr = reinterpret_cast<float4*>(out + (size_t)b * T);
    const int nv = T >> 2;            // float4 steps
    constexpr int D = 16;             // prefetch depth: 16*4 steps * ~26cy ≈ 1600cy > HBM RTT

    float4 buf[D];
    #pragma unroll
    for (int i = 0; i < D; ++i) buf[i] = xr[i];

    float EF = 0.0f, ES = 0.0f, Y = 0.0f;

    for (int v = 0; v < nv; v += D) {
        #pragma unroll
        for (int i = 0; i < D; ++i) {
            float4 xv = buf[i];
            int nxt = v + D + i;
            if (nxt < nv) buf[i] = xr[nxt];   // uniform guard; refill pipeline
            float4 yo;
#define SSL_STEP(XV, YOUT) { \
            float sx2 = fmaf(nhs, (XV), hst); \
            float u2  = fmaf(nq, Y, sx2); \
            float t2  = fminf(u2, 0.0f); \
            float rY  = r * Y; \
            bool att  = sx2 < rY; \
            float af  = att ? a_af : a_sf; \
            float as2 = att ? a_as : a_ss; \
            float dF  = EF - t2; \
            float dS  = ES - t2; \
            EF = fmaf(af, dF, t2); \
            ES = fmaf(as2, dS, t2); \
            Y  = EF + ES; \
            (YOUT) = Y; }
            SSL_STEP(xv.x, yo.x)
            SSL_STEP(xv.y, yo.y)
            SSL_STEP(xv.z, yo.z)
            SSL_STEP(xv.w, yo.w)
#undef SSL_STEP
            yr[v + i] = yo;
        }
    }
}

extern "C" void kernel_launch(void* const* d_in, const int* in_sizes, int n_in,
                              void* d_out, int out_size, void* d_ws, size_t ws_size,
                              hipStream_t stream) {
    const float* x = (const float*)d_in[0];
    const int T = 131072;
    const int B = in_sizes[0] / T;

    dim3 block(64);
    dim3 grid((B + 63) / 64);   // 2 blocks of 64 -> 2 waves, likely on different CUs
    ssl_comp_serial<<<grid, block, 0, stream>>>(
        x, (float*)d_out,
        (const float*)d_in[1], (const float*)d_in[2], (const float*)d_in[3],
        (const float*)d_in[4], (const float*)d_in[5], (const float*)d_in[6],
        (const float*)d_in[7], B, T);
}

// Round 4
// 572.954 us; speedup vs baseline: 6.4892x; 6.4892x over previous
//
#include <hip/hip_runtime.h>
#include <math.h>

// SSL compressor gain: 128 independent nonlinear 2-state IIR chains, T=131072.
// Round 4: chunk maps + Newton correction with exact per-chunk Jacobians.
//   Round 3 (diagonal map + linear interp compose) hit absmax 0.25 vs 0.2175:
//   first-order handoff error. Now the interp compose only provides a GUESS;
//   a parallel pass reruns each chunk from its guess state propagating the
//   exact 2x2 Jacobian (the map is affine conditioned on gate sequences), and
//   a serial Newton compose makes boundary states exact to ~1e-2 (gate-flip
//   noise only). Final pass reruns chunks from corrected states.

struct SslParams { float nhs, hst, nq, r, a_af, a_as, a_sf, a_ss; };

__device__ __forceinline__ double dsecs(double u, double tmin, double tmax) {
    double s = 1.0 / (1.0 + exp(-u));
    return tmin + (tmax - tmin) * s;
}

__device__ __forceinline__ SslParams ssl_params(
        const float* cth, const float* rl, const float* fbl,
        const float* uaf, const float* uas, const float* usf, const float* uss) {
    const double FS = 44100.0;
    const double T_AF_MIN = 820.0 * 4.7e-07 * 0.8,   T_AF_MAX = 270000.0 * 4.7e-07 * 1.2;
    const double T_AS_MIN = 820.0 * 6.8e-06 * 0.8,   T_AS_MAX = 270000.0 * 6.8e-06 * 100.0;
    const double T_SF_MIN = 91000.0 * 4.7e-07 * 0.8, T_SF_MAX = 1200000.0 * 4.7e-07 * 1.2;
    const double T_SS_MIN = 750000.0 * 6.8e-06 * 0.8, T_SS_MAX = 750000.0 * 6.8e-06 * 100.0;

    double cr    = fmax(exp((double)rl[0]) + 1.0, 1.0 + 1e-4);
    double fb    = 1.0 / (1.0 + exp(-(double)fbl[0]));
    double slope = 1.0 - 1.0 / cr;

    SslParams p;
    p.a_af = (float)exp(-1.0 / (FS * dsecs((double)uaf[0], T_AF_MIN, T_AF_MAX)));
    p.a_as = (float)exp(-1.0 / (FS * dsecs((double)uas[0], T_AS_MIN, T_AS_MAX)));
    p.a_sf = (float)exp(-1.0 / (FS * dsecs((double)usf[0], T_SF_MIN, T_SF_MAX)));
    p.a_ss = (float)exp(-1.0 / (FS * dsecs((double)uss[0], T_SS_MIN, T_SS_MAX)));
    double q = 0.5 * slope * fb;          // feedback coupling in scaled domain
    p.nq  = (float)(-q);
    p.r   = (float)(0.5 + q);             // gate: att <=> sx2 < r*Y
    p.nhs = (float)(-0.5 * slope);        // sx2 = nhs*x + hst
    p.hst = (float)(0.5 * slope * (double)cth[0]);
    return p;
}

constexpr int   T_LEN   = 131072;
constexpr int   NCHUNK  = 32;
constexpr int   CHUNK   = T_LEN / NCHUNK;   // 4096
constexpr int   K       = 33;               // ES_in nodes: 0, -0.25, ..., -8.0
constexpr float STEP_ES = 0.25f;
constexpr int   DPF     = 8;                // float4 prefetch depth
constexpr int   NV_ROW  = T_LEN >> 2;       // float4 per row

// Scaled-state recurrence (EF=-ef/2, ES=-es/2, Y=EF+ES=y_prev):
//   sx2 = -0.5*slope*(x - thresh);  u2 = sx2 + nq*Y;  t2 = min(u2,0) = -tgt/2
//   att = sx2 < r*Y;  EF' = t2 + af*(EF-t2);  ES' = t2 + as*(ES-t2);  y = EF'+ES'
template<bool STORE>
__device__ __forceinline__ void run_chunk(const float4* __restrict__ xr,
                                          float4* __restrict__ yr,
                                          int v0, int v1,
                                          float& EF, float& ES,
                                          const SslParams& P)
{
    const float nhs = P.nhs, hst = P.hst, nq = P.nq, r = P.r;
    const float a_af = P.a_af, a_as = P.a_as, a_sf = P.a_sf, a_ss = P.a_ss;
    float Y = EF + ES;

    float4 buf[DPF];
    #pragma unroll
    for (int i = 0; i < DPF; ++i) buf[i] = xr[v0 + i];

    for (int v = v0; v < v1; v += DPF) {
        #pragma unroll
        for (int i = 0; i < DPF; ++i) {
            float4 xv = buf[i];
            int nxt = v + DPF + i;
            if (nxt < NV_ROW) buf[i] = xr[nxt];
            float4 yo;
#define SSL_STEP(XV, YOUT) { \
            float sx2 = fmaf(nhs, (XV), hst); \
            float u2  = fmaf(nq, Y, sx2); \
            float t2  = fminf(u2, 0.0f); \
            float rY  = r * Y; \
            bool att  = sx2 < rY; \
            float af  = att ? a_af : a_sf; \
            float as2 = att ? a_as : a_ss; \
            float dF  = EF - t2; \
            float dS  = ES - t2; \
            EF = fmaf(af, dF, t2); \
            ES = fmaf(as2, dS, t2); \
            Y  = EF + ES; \
            (YOUT) = Y; }
            SSL_STEP(xv.x, yo.x)
            SSL_STEP(xv.y, yo.y)
            SSL_STEP(xv.z, yo.z)
            SSL_STEP(xv.w, yo.w)
#undef SSL_STEP
            if (STORE) yr[v + i] = yo;
        }
    }
}

// Chunk run with forward-mode 2x2 Jacobian d(EF,ES)_out / d(EF,ES)_in.
// Conditioned on the realized gates the map is affine, so J is exact.
__device__ __forceinline__ void run_chunk_jac(const float4* __restrict__ xr,
                                              int v0, int v1,
                                              float& EF, float& ES,
                                              float4& J,   // (jFx,jFy,jSx,jSy)
                                              const SslParams& P)
{
    const float nhs = P.nhs, hst = P.hst, nq = P.nq, r = P.r;
    const float a_af = P.a_af, a_as = P.a_as, a_sf = P.a_sf, a_ss = P.a_ss;
    float Y = EF + ES;
    float jFx = 1.0f, jFy = 0.0f, jSx = 0.0f, jSy = 1.0f;

    float4 buf[DPF];
    #pragma unroll
    for (int i = 0; i < DPF; ++i) buf[i] = xr[v0 + i];

    for (int v = v0; v < v1; v += DPF) {
        #pragma unroll
        for (int i = 0; i < DPF; ++i) {
            float4 xv = buf[i];
            int nxt = v + DPF + i;
            if (nxt < NV_ROW) buf[i] = xr[nxt];
#define SSL_STEP_J(XV) { \
            float sx2 = fmaf(nhs, (XV), hst); \
            float u2  = fmaf(nq, Y, sx2); \
            float t2  = fminf(u2, 0.0f); \
            bool g2   = u2 < 0.0f; \
            bool att  = sx2 < r * Y; \
            float af  = att ? a_af : a_sf; \
            float as2 = att ? a_as : a_ss; \
            float jYx = jFx + jSx, jYy = jFy + jSy; \
            float jtx = g2 ? nq * jYx : 0.0f; \
            float jty = g2 ? nq * jYy : 0.0f; \
            jFx = fmaf(af,  jFx - jtx, jtx); \
            jFy = fmaf(af,  jFy - jty, jty); \
            jSx = fmaf(as2, jSx - jtx, jtx); \
            jSy = fmaf(as2, jSy - jty, jty); \
            EF  = fmaf(af,  EF - t2, t2); \
            ES  = fmaf(as2, ES - t2, t2); \
            Y   = EF + ES; }
            SSL_STEP_J(xv.x)
            SSL_STEP_J(xv.y)
            SSL_STEP_J(xv.z)
            SSL_STEP_J(xv.w)
#undef SSL_STEP_J
        }
    }
    J = make_float4(jFx, jFy, jSx, jSy);
}

// Pass 1: diagonal chunk maps at K ES-nodes (coarse model for the guess).
__global__ __launch_bounds__(256) void ssl_map(
        const float* __restrict__ x, float2* __restrict__ mp,
        const float* cth, const float* rl, const float* fbl,
        const float* uaf, const float* uas, const float* usf, const float* uss,
        int B)
{
    int tid = blockIdx.x * 256 + threadIdx.x;
    int k  = tid % K;
    int bc = tid / K;
    int c  = bc % NCHUNK;
    int b  = bc / NCHUNK;
    if (b >= B) return;

    SslParams P = ssl_params(cth, rl, fbl, uaf, uas, usf, uss);
    float v0s = -STEP_ES * (float)k;
    float EF = v0s, ES = v0s;
    const float4* xr = reinterpret_cast<const float4*>(x + (size_t)b * T_LEN);
    run_chunk<false>(xr, nullptr, (c * CHUNK) >> 2, ((c + 1) * CHUNK) >> 2, EF, ES, P);
    mp[tid] = make_float2(EF, ES);
}

// Pass 2: serial interp compose -> boundary GUESSES s0_c (state before chunk c).
__global__ __launch_bounds__(64) void ssl_compose0(
        const float2* __restrict__ mp, float2* __restrict__ bnd0, int B)
{
    int b = blockIdx.x * 64 + threadIdx.x;
    if (b >= B) return;
    float EF = 0.0f, ES = 0.0f;
    for (int c = 0; c < NCHUNK; ++c) {
        bnd0[b * NCHUNK + c] = make_float2(EF, ES);
        float t = (-ES) / STEP_ES;
        int idx = (int)t;
        if (idx > K - 2) idx = K - 2;
        float u = t - (float)idx;
        const float2* m = &mp[(size_t)(b * NCHUNK + c) * K];
        float2 m0 = m[idx], m1 = m[idx + 1];
        EF = m0.x + (m1.x - m0.x) * u;
        ES = m0.y + (m1.y - m0.y) * u;
    }
}

// Pass 3: parallel exact runs from guesses, with exact Jacobians.
__global__ __launch_bounds__(64) void ssl_jac(
        const float* __restrict__ x,
        const float2* __restrict__ bnd0,
        float2* __restrict__ Fv, float4* __restrict__ Jv,
        const float* cth, const float* rl, const float* fbl,
        const float* uaf, const float* uas, const float* usf, const float* uss,
        int B)
{
    int tid = blockIdx.x * 64 + threadIdx.x;
    int b = tid % B;
    int c = tid / B;
    if (c >= NCHUNK) return;

    SslParams P = ssl_params(cth, rl, fbl, uaf, uas, usf, uss);
    float2 s = bnd0[b * NCHUNK + c];
    float EF = s.x, ES = s.y;
    float4 J;
    const float4* xr = reinterpret_cast<const float4*>(x + (size_t)b * T_LEN);
    run_chunk_jac(xr, (c * CHUNK) >> 2, ((c + 1) * CHUNK) >> 2, EF, ES, J, P);
    Fv[b * NCHUNK + c] = make_float2(EF, ES);
    Jv[b * NCHUNK + c] = J;
}

// Pass 4: serial Newton compose: s_{c+1} = F_c + J_c * (s_c - s0_c).
__global__ __launch_bounds__(64) void ssl_compose1(
        const float2* __restrict__ bnd0,
        const float2* __restrict__ Fv, const float4* __restrict__ Jv,
        float2* __restrict__ bnd1, int B)
{
    int b = blockIdx.x * 64 + threadIdx.x;
    if (b >= B) return;
    float sx = 0.0f, sy = 0.0f;
    for (int c = 0; c < NCHUNK; ++c) {
        int i = b * NCHUNK + c;
        bnd1[i] = make_float2(sx, sy);
        float2 s0 = bnd0[i];
        float2 F  = Fv[i];
        float4 J  = Jv[i];
        float dx = sx - s0.x, dy = sy - s0.y;
        sx = F.x + J.x * dx + J.y * dy;
        sy = F.y + J.z * dx + J.w * dy;
    }
}

// Pass 5: rerun each chunk from its corrected boundary state, store outputs.
__global__ __launch_bounds__(64) void ssl_out(
        const float* __restrict__ x, float* __restrict__ out,
        const float2* __restrict__ bnd,
        const float* cth, const float* rl, const float* fbl,
        const float* uaf, const float* uas, const float* usf, const float* uss,
        int B)
{
    int tid = blockIdx.x * 64 + threadIdx.x;
    int b = tid % B;
    int c = tid / B;
    if (c >= NCHUNK) return;

    SslParams P = ssl_params(cth, rl, fbl, uaf, uas, usf, uss);
    float2 s = bnd[b * NCHUNK + c];
    float EF = s.x, ES = s.y;
    const float4* xr = reinterpret_cast<const float4*>(x + (size_t)b * T_LEN);
    float4* yr       = reinterpret_cast<float4*>(out + (size_t)b * T_LEN);
    run_chunk<true>(xr, yr, (c * CHUNK) >> 2, ((c + 1) * CHUNK) >> 2, EF, ES, P);
}

extern "C" void kernel_launch(void* const* d_in, const int* in_sizes, int n_in,
                              void* d_out, int out_size, void* d_ws, size_t ws_size,
                              hipStream_t stream) {
    const float* x = (const float*)d_in[0];
    const int B = in_sizes[0] / T_LEN;   // 128
    const int NC = B * NCHUNK;           // 4096

    float2* mp   = (float2*)d_ws;                 // [B][NCHUNK][K]
    float2* bnd0 = mp + (size_t)NC * K;           // [B][NCHUNK] guesses
    float2* Fv   = bnd0 + NC;                     // [B][NCHUNK] exact ends from guesses
    float2* bnd1 = Fv + NC;                       // [B][NCHUNK] corrected
    float4* Jv   = (float4*)(bnd1 + NC);          // [B][NCHUNK] Jacobians

    const float* cth = (const float*)d_in[1];
    const float* rl  = (const float*)d_in[2];
    const float* fbl = (const float*)d_in[3];
    const float* uaf = (const float*)d_in[4];
    const float* uas = (const float*)d_in[5];
    const float* usf = (const float*)d_in[6];
    const float* uss = (const float*)d_in[7];

    int map_threads = NC * K;
    ssl_map<<<(map_threads + 255) / 256, 256, 0, stream>>>(
        x, mp, cth, rl, fbl, uaf, uas, usf, uss, B);

    ssl_compose0<<<(B + 63) / 64, 64, 0, stream>>>(mp, bnd0, B);

    ssl_jac<<<(NC + 63) / 64, 64, 0, stream>>>(
        x, bnd0, Fv, Jv, cth, rl, fbl, uaf, uas, usf, uss, B);

    ssl_compose1<<<(B + 63) / 64, 64, 0, stream>>>(bnd0, Fv, Jv, bnd1, B);

    ssl_out<<<(NC + 63) / 64, 64, 0, stream>>>(
        x, (float*)d_out, bnd1, cth, rl, fbl, uaf, uas, usf, uss, B);
}

// Round 5
// 321.368 us; speedup vs baseline: 11.5693x; 1.7829x over previous
//
#include <hip/hip_runtime.h>
#include <math.h>

// SSL compressor gain: 128 independent nonlinear 2-state IIR chains, T=131072.
// Round 5: same structure as round 4 (map -> interp compose -> exact-Jacobian
// Newton compose -> out), retuned from rocprof evidence:
//   - map was VALU-throughput-bound (87% busy, 237us, work = K*B*T): K 33->17.
//   - jac/out are latency-bound serial chains: NCHUNK 32->64 halves their
//     length (CHUNK=2048 -> ~60-80us each).
// Newton anchor (round 3->4): guesses within ~0.25 converge to the f32 noise
// floor (0.0625). h=0.5 interp guesses stay within ~0.3-0.5 of truth.

struct SslParams { float nhs, hst, nq, r, a_af, a_as, a_sf, a_ss; };

__device__ __forceinline__ double dsecs(double u, double tmin, double tmax) {
    double s = 1.0 / (1.0 + exp(-u));
    return tmin + (tmax - tmin) * s;
}

__device__ __forceinline__ SslParams ssl_params(
        const float* cth, const float* rl, const float* fbl,
        const float* uaf, const float* uas, const float* usf, const float* uss) {
    const double FS = 44100.0;
    const double T_AF_MIN = 820.0 * 4.7e-07 * 0.8,   T_AF_MAX = 270000.0 * 4.7e-07 * 1.2;
    const double T_AS_MIN = 820.0 * 6.8e-06 * 0.8,   T_AS_MAX = 270000.0 * 6.8e-06 * 100.0;
    const double T_SF_MIN = 91000.0 * 4.7e-07 * 0.8, T_SF_MAX = 1200000.0 * 4.7e-07 * 1.2;
    const double T_SS_MIN = 750000.0 * 6.8e-06 * 0.8, T_SS_MAX = 750000.0 * 6.8e-06 * 100.0;

    double cr    = fmax(exp((double)rl[0]) + 1.0, 1.0 + 1e-4);
    double fb    = 1.0 / (1.0 + exp(-(double)fbl[0]));
    double slope = 1.0 - 1.0 / cr;

    SslParams p;
    p.a_af = (float)exp(-1.0 / (FS * dsecs((double)uaf[0], T_AF_MIN, T_AF_MAX)));
    p.a_as = (float)exp(-1.0 / (FS * dsecs((double)uas[0], T_AS_MIN, T_AS_MAX)));
    p.a_sf = (float)exp(-1.0 / (FS * dsecs((double)usf[0], T_SF_MIN, T_SF_MAX)));
    p.a_ss = (float)exp(-1.0 / (FS * dsecs((double)uss[0], T_SS_MIN, T_SS_MAX)));
    double q = 0.5 * slope * fb;          // feedback coupling in scaled domain
    p.nq  = (float)(-q);
    p.r   = (float)(0.5 + q);             // gate: att <=> sx2 < r*Y
    p.nhs = (float)(-0.5 * slope);        // sx2 = nhs*x + hst
    p.hst = (float)(0.5 * slope * (double)cth[0]);
    return p;
}

constexpr int   T_LEN   = 131072;
constexpr int   NCHUNK  = 64;
constexpr int   CHUNK   = T_LEN / NCHUNK;   // 2048
constexpr int   K       = 17;               // ES_in nodes: 0, -0.5, ..., -8.0
constexpr float STEP_ES = 0.5f;
constexpr int   DPF     = 8;                // float4 prefetch depth
constexpr int   NV_ROW  = T_LEN >> 2;       // float4 per row

// Scaled-state recurrence (EF=-ef/2, ES=-es/2, Y=EF+ES=y_prev):
//   sx2 = -0.5*slope*(x - thresh);  u2 = sx2 + nq*Y;  t2 = min(u2,0) = -tgt/2
//   att = sx2 < r*Y;  EF' = t2 + af*(EF-t2);  ES' = t2 + as*(ES-t2);  y = EF'+ES'
template<bool STORE>
__device__ __forceinline__ void run_chunk(const float4* __restrict__ xr,
                                          float4* __restrict__ yr,
                                          int v0, int v1,
                                          float& EF, float& ES,
                                          const SslParams& P)
{
    const float nhs = P.nhs, hst = P.hst, nq = P.nq, r = P.r;
    const float a_af = P.a_af, a_as = P.a_as, a_sf = P.a_sf, a_ss = P.a_ss;
    float Y = EF + ES;

    float4 buf[DPF];
    #pragma unroll
    for (int i = 0; i < DPF; ++i) buf[i] = xr[v0 + i];

    for (int v = v0; v < v1; v += DPF) {
        #pragma unroll
        for (int i = 0; i < DPF; ++i) {
            float4 xv = buf[i];
            int nxt = v + DPF + i;
            if (nxt < NV_ROW) buf[i] = xr[nxt];
            float4 yo;
#define SSL_STEP(XV, YOUT) { \
            float sx2 = fmaf(nhs, (XV), hst); \
            float u2  = fmaf(nq, Y, sx2); \
            float t2  = fminf(u2, 0.0f); \
            float rY  = r * Y; \
            bool att  = sx2 < rY; \
            float af  = att ? a_af : a_sf; \
            float as2 = att ? a_as : a_ss; \
            float dF  = EF - t2; \
            float dS  = ES - t2; \
            EF = fmaf(af, dF, t2); \
            ES = fmaf(as2, dS, t2); \
            Y  = EF + ES; \
            (YOUT) = Y; }
            SSL_STEP(xv.x, yo.x)
            SSL_STEP(xv.y, yo.y)
            SSL_STEP(xv.z, yo.z)
            SSL_STEP(xv.w, yo.w)
#undef SSL_STEP
            if (STORE) yr[v + i] = yo;
        }
    }
}

// Chunk run with forward-mode 2x2 Jacobian d(EF,ES)_out / d(EF,ES)_in.
// Conditioned on the realized gates the map is affine, so J is exact.
__device__ __forceinline__ void run_chunk_jac(const float4* __restrict__ xr,
                                              int v0, int v1,
                                              float& EF, float& ES,
                                              float4& J,   // (jFx,jFy,jSx,jSy)
                                              const SslParams& P)
{
    const float nhs = P.nhs, hst = P.hst, nq = P.nq, r = P.r;
    const float a_af = P.a_af, a_as = P.a_as, a_sf = P.a_sf, a_ss = P.a_ss;
    float Y = EF + ES;
    float jFx = 1.0f, jFy = 0.0f, jSx = 0.0f, jSy = 1.0f;

    float4 buf[DPF];
    #pragma unroll
    for (int i = 0; i < DPF; ++i) buf[i] = xr[v0 + i];

    for (int v = v0; v < v1; v += DPF) {
        #pragma unroll
        for (int i = 0; i < DPF; ++i) {
            float4 xv = buf[i];
            int nxt = v + DPF + i;
            if (nxt < NV_ROW) buf[i] = xr[nxt];
#define SSL_STEP_J(XV) { \
            float sx2 = fmaf(nhs, (XV), hst); \
            float u2  = fmaf(nq, Y, sx2); \
            float t2  = fminf(u2, 0.0f); \
            bool g2   = u2 < 0.0f; \
            bool att  = sx2 < r * Y; \
            float af  = att ? a_af : a_sf; \
            float as2 = att ? a_as : a_ss; \
            float jYx = jFx + jSx, jYy = jFy + jSy; \
            float jtx = g2 ? nq * jYx : 0.0f; \
            float jty = g2 ? nq * jYy : 0.0f; \
            jFx = fmaf(af,  jFx - jtx, jtx); \
            jFy = fmaf(af,  jFy - jty, jty); \
            jSx = fmaf(as2, jSx - jtx, jtx); \
            jSy = fmaf(as2, jSy - jty, jty); \
            EF  = fmaf(af,  EF - t2, t2); \
            ES  = fmaf(as2, ES - t2, t2); \
            Y   = EF + ES; }
            SSL_STEP_J(xv.x)
            SSL_STEP_J(xv.y)
            SSL_STEP_J(xv.z)
            SSL_STEP_J(xv.w)
#undef SSL_STEP_J
        }
    }
    J = make_float4(jFx, jFy, jSx, jSy);
}

// Pass 1: diagonal chunk maps at K ES-nodes (coarse model for the guess).
__global__ __launch_bounds__(256) void ssl_map(
        const float* __restrict__ x, float2* __restrict__ mp,
        const float* cth, const float* rl, const float* fbl,
        const float* uaf, const float* uas, const float* usf, const float* uss,
        int B)
{
    int tid = blockIdx.x * 256 + threadIdx.x;
    int k  = tid % K;
    int bc = tid / K;
    int c  = bc % NCHUNK;
    int b  = bc / NCHUNK;
    if (b >= B) return;

    SslParams P = ssl_params(cth, rl, fbl, uaf, uas, usf, uss);
    float v0s = -STEP_ES * (float)k;
    float EF = v0s, ES = v0s;
    const float4* xr = reinterpret_cast<const float4*>(x + (size_t)b * T_LEN);
    run_chunk<false>(xr, nullptr, (c * CHUNK) >> 2, ((c + 1) * CHUNK) >> 2, EF, ES, P);
    mp[tid] = make_float2(EF, ES);
}

// Pass 2: serial interp compose -> boundary GUESSES s0_c (state before chunk c).
__global__ __launch_bounds__(64) void ssl_compose0(
        const float2* __restrict__ mp, float2* __restrict__ bnd0, int B)
{
    int b = blockIdx.x * 64 + threadIdx.x;
    if (b >= B) return;
    float EF = 0.0f, ES = 0.0f;
    for (int c = 0; c < NCHUNK; ++c) {
        bnd0[b * NCHUNK + c] = make_float2(EF, ES);
        float t = (-ES) / STEP_ES;
        int idx = (int)t;
        if (idx > K - 2) idx = K - 2;
        float u = t - (float)idx;
        const float2* m = &mp[(size_t)(b * NCHUNK + c) * K];
        float2 m0 = m[idx], m1 = m[idx + 1];
        EF = m0.x + (m1.x - m0.x) * u;
        ES = m0.y + (m1.y - m0.y) * u;
    }
}

// Pass 3: parallel exact runs from guesses, with exact Jacobians.
__global__ __launch_bounds__(64) void ssl_jac(
        const float* __restrict__ x,
        const float2* __restrict__ bnd0,
        float2* __restrict__ Fv, float4* __restrict__ Jv,
        const float* cth, const float* rl, const float* fbl,
        const float* uaf, const float* uas, const float* usf, const float* uss,
        int B)
{
    int tid = blockIdx.x * 64 + threadIdx.x;
    int b = tid % B;
    int c = tid / B;
    if (c >= NCHUNK) return;

    SslParams P = ssl_params(cth, rl, fbl, uaf, uas, usf, uss);
    float2 s = bnd0[b * NCHUNK + c];
    float EF = s.x, ES = s.y;
    float4 J;
    const float4* xr = reinterpret_cast<const float4*>(x + (size_t)b * T_LEN);
    run_chunk_jac(xr, (c * CHUNK) >> 2, ((c + 1) * CHUNK) >> 2, EF, ES, J, P);
    Fv[b * NCHUNK + c] = make_float2(EF, ES);
    Jv[b * NCHUNK + c] = J;
}

// Pass 4: serial Newton compose: s_{c+1} = F_c + J_c * (s_c - s0_c).
__global__ __launch_bounds__(64) void ssl_compose1(
        const float2* __restrict__ bnd0,
        const float2* __restrict__ Fv, const float4* __restrict__ Jv,
        float2* __restrict__ bnd1, int B)
{
    int b = blockIdx.x * 64 + threadIdx.x;
    if (b >= B) return;
    float sx = 0.0f, sy = 0.0f;
    for (int c = 0; c < NCHUNK; ++c) {
        int i = b * NCHUNK + c;
        bnd1[i] = make_float2(sx, sy);
        float2 s0 = bnd0[i];
        float2 F  = Fv[i];
        float4 J  = Jv[i];
        float dx = sx - s0.x, dy = sy - s0.y;
        sx = F.x + J.x * dx + J.y * dy;
        sy = F.y + J.z * dx + J.w * dy;
    }
}

// Pass 5: rerun each chunk from its corrected boundary state, store outputs.
__global__ __launch_bounds__(64) void ssl_out(
        const float* __restrict__ x, float* __restrict__ out,
        const float2* __restrict__ bnd,
        const float* cth, const float* rl, const float* fbl,
        const float* uaf, const float* uas, const float* usf, const float* uss,
        int B)
{
    int tid = blockIdx.x * 64 + threadIdx.x;
    int b = tid % B;
    int c = tid / B;
    if (c >= NCHUNK) return;

    SslParams P = ssl_params(cth, rl, fbl, uaf, uas, usf, uss);
    float2 s = bnd[b * NCHUNK + c];
    float EF = s.x, ES = s.y;
    const float4* xr = reinterpret_cast<const float4*>(x + (size_t)b * T_LEN);
    float4* yr       = reinterpret_cast<float4*>(out + (size_t)b * T_LEN);
    run_chunk<true>(xr, yr, (c * CHUNK) >> 2, ((c + 1) * CHUNK) >> 2, EF, ES, P);
}

extern "C" void kernel_launch(void* const* d_in, const int* in_sizes, int n_in,
                              void* d_out, int out_size, void* d_ws, size_t ws_size,
                              hipStream_t stream) {
    const float* x = (const float*)d_in[0];
    const int B = in_sizes[0] / T_LEN;   // 128
    const int NC = B * NCHUNK;           // 8192

    float2* mp   = (float2*)d_ws;                 // [B][NCHUNK][K]
    float2* bnd0 = mp + (size_t)NC * K;           // [B][NCHUNK] guesses
    float2* Fv   = bnd0 + NC;                     // [B][NCHUNK] exact ends from guesses
    float2* bnd1 = Fv + NC;                       // [B][NCHUNK] corrected
    float4* Jv   = (float4*)(bnd1 + NC);          // [B][NCHUNK] Jacobians

    const float* cth = (const float*)d_in[1];
    const float* rl  = (const float*)d_in[2];
    const float* fbl = (const float*)d_in[3];
    const float* uaf = (const float*)d_in[4];
    const float* uas = (const float*)d_in[5];
    const float* usf = (const float*)d_in[6];
    const float* uss = (const float*)d_in[7];

    int map_threads = NC * K;
    ssl_map<<<(map_threads + 255) / 256, 256, 0, stream>>>(
        x, mp, cth, rl, fbl, uaf, uas, usf, uss, B);

    ssl_compose0<<<(B + 63) / 64, 64, 0, stream>>>(mp, bnd0, B);

    ssl_jac<<<(NC + 63) / 64, 64, 0, stream>>>(
        x, bnd0, Fv, Jv, cth, rl, fbl, uaf, uas, usf, uss, B);

    ssl_compose1<<<(B + 63) / 64, 64, 0, stream>>>(bnd0, Fv, Jv, bnd1, B);

    ssl_out<<<(NC + 63) / 64, 64, 0, stream>>>(
        x, (float*)d_out, bnd1, cth, rl, fbl, uaf, uas, usf, uss, B);
}

// Round 7
// 250.196 us; speedup vs baseline: 14.8603x; 1.2845x over previous
//
#include <hip/hip_runtime.h>
#include <math.h>

// SSL compressor gain: 128 independent nonlinear 2-state IIR chains, T=131072.
// Round 7: round-6 structure + SECOND Newton iteration.
//   Round 6 failed (0.3125): intermediate snapshot guesses carry ~50% of the
//   diagonal-init EF error (EF forget factor at 512 steps ~ 0.5 vs 0.07 at
//   2048), so guess err was ~0.7-1.0 and the single Newton step's residual
//   (empirically ~0.6*delta^2: r4 0.25->0.03, r5 0.45->0.15) landed at ~0.3.
//   Fix: iterate Newton twice at fine (512-step) granularity. Iter-2 from
//   delta~0.31 -> res ~0.06 (+0.06 f32 noise). Jac/compose buffers reused.

struct SslParams { float nhs, hst, nq, r, a_af, a_as, a_sf, a_ss; };

__device__ __forceinline__ double dsecs(double u, double tmin, double tmax) {
    double s = 1.0 / (1.0 + exp(-u));
    return tmin + (tmax - tmin) * s;
}

__device__ __forceinline__ SslParams ssl_params(
        const float* cth, const float* rl, const float* fbl,
        const float* uaf, const float* uas, const float* usf, const float* uss) {
    const double FS = 44100.0;
    const double T_AF_MIN = 820.0 * 4.7e-07 * 0.8,   T_AF_MAX = 270000.0 * 4.7e-07 * 1.2;
    const double T_AS_MIN = 820.0 * 6.8e-06 * 0.8,   T_AS_MAX = 270000.0 * 6.8e-06 * 100.0;
    const double T_SF_MIN = 91000.0 * 4.7e-07 * 0.8, T_SF_MAX = 1200000.0 * 4.7e-07 * 1.2;
    const double T_SS_MIN = 750000.0 * 6.8e-06 * 0.8, T_SS_MAX = 750000.0 * 6.8e-06 * 100.0;

    double cr    = fmax(exp((double)rl[0]) + 1.0, 1.0 + 1e-4);
    double fb    = 1.0 / (1.0 + exp(-(double)fbl[0]));
    double slope = 1.0 - 1.0 / cr;

    SslParams p;
    p.a_af = (float)exp(-1.0 / (FS * dsecs((double)uaf[0], T_AF_MIN, T_AF_MAX)));
    p.a_as = (float)exp(-1.0 / (FS * dsecs((double)uas[0], T_AS_MIN, T_AS_MAX)));
    p.a_sf = (float)exp(-1.0 / (FS * dsecs((double)usf[0], T_SF_MIN, T_SF_MAX)));
    p.a_ss = (float)exp(-1.0 / (FS * dsecs((double)uss[0], T_SS_MIN, T_SS_MAX)));
    double q = 0.5 * slope * fb;          // feedback coupling in scaled domain
    p.nq  = (float)(-q);
    p.r   = (float)(0.5 + q);             // gate: att <=> sx2 < r*Y
    p.nhs = (float)(-0.5 * slope);        // sx2 = nhs*x + hst
    p.hst = (float)(0.5 * slope * (double)cth[0]);
    return p;
}

constexpr int   T_LEN    = 131072;
constexpr int   NCM      = 64;              // map chunks
constexpr int   CM       = T_LEN / NCM;     // 2048
constexpr int   SUB      = 4;               // snapshots per map chunk
constexpr int   SL       = CM / SUB;        // 512
constexpr int   NC       = NCM * SUB;       // 256 fine chunks
constexpr int   CF       = T_LEN / NC;      // 512
constexpr int   K        = 16;              // ES nodes: 0 .. -8, h=8/15
constexpr float STEP_ES  = 8.0f / 15.0f;
constexpr float INV_STEP = 15.0f / 8.0f;
constexpr int   DPF      = 8;               // float4 prefetch depth
constexpr int   NV_ROW   = T_LEN >> 2;

// Scaled-state recurrence (EF=-ef/2, ES=-es/2, Y=EF+ES=y_prev):
//   sx2 = -0.5*slope*(x - thresh);  u2 = sx2 + nq*Y;  t2 = min(u2,0) = -tgt/2
//   att = sx2 < r*Y;  EF' = t2 + af*(EF-t2);  ES' = t2 + as*(ES-t2);  y = EF'+ES'
template<bool STORE>
__device__ __forceinline__ void run_chunk(const float4* __restrict__ xr,
                                          float4* __restrict__ yr,
                                          int v0, int v1,
                                          float& EF, float& ES,
                                          const SslParams& P)
{
    const float nhs = P.nhs, hst = P.hst, nq = P.nq, r = P.r;
    const float a_af = P.a_af, a_as = P.a_as, a_sf = P.a_sf, a_ss = P.a_ss;
    float Y = EF + ES;

    float4 buf[DPF];
    #pragma unroll
    for (int i = 0; i < DPF; ++i) buf[i] = xr[v0 + i];

    for (int v = v0; v < v1; v += DPF) {
        #pragma unroll
        for (int i = 0; i < DPF; ++i) {
            float4 xv = buf[i];
            int nxt = v + DPF + i;
            if (nxt < NV_ROW) buf[i] = xr[nxt];
            float4 yo;
#define SSL_STEP(XV, YOUT) { \
            float sx2 = fmaf(nhs, (XV), hst); \
            float u2  = fmaf(nq, Y, sx2); \
            float t2  = fminf(u2, 0.0f); \
            float rY  = r * Y; \
            bool att  = sx2 < rY; \
            float af  = att ? a_af : a_sf; \
            float as2 = att ? a_as : a_ss; \
            float dF  = EF - t2; \
            float dS  = ES - t2; \
            EF = fmaf(af, dF, t2); \
            ES = fmaf(as2, dS, t2); \
            Y  = EF + ES; \
            (YOUT) = Y; }
            SSL_STEP(xv.x, yo.x)
            SSL_STEP(xv.y, yo.y)
            SSL_STEP(xv.z, yo.z)
            SSL_STEP(xv.w, yo.w)
#undef SSL_STEP
            if (STORE) yr[v + i] = yo;
        }
    }
}

// Chunk run with forward-mode 2x2 Jacobian d(EF,ES)_out / d(EF,ES)_in.
// Conditioned on the realized gates the map is affine, so J is exact.
__device__ __forceinline__ void run_chunk_jac(const float4* __restrict__ xr,
                                              int v0, int v1,
                                              float& EF, float& ES,
                                              float4& J,   // (jFx,jFy,jSx,jSy)
                                              const SslParams& P)
{
    const float nhs = P.nhs, hst = P.hst, nq = P.nq, r = P.r;
    const float a_af = P.a_af, a_as = P.a_as, a_sf = P.a_sf, a_ss = P.a_ss;
    float Y = EF + ES;
    float jFx = 1.0f, jFy = 0.0f, jSx = 0.0f, jSy = 1.0f;

    float4 buf[DPF];
    #pragma unroll
    for (int i = 0; i < DPF; ++i) buf[i] = xr[v0 + i];

    for (int v = v0; v < v1; v += DPF) {
        #pragma unroll
        for (int i = 0; i < DPF; ++i) {
            float4 xv = buf[i];
            int nxt = v + DPF + i;
            if (nxt < NV_ROW) buf[i] = xr[nxt];
#define SSL_STEP_J(XV) { \
            float sx2 = fmaf(nhs, (XV), hst); \
            float u2  = fmaf(nq, Y, sx2); \
            float t2  = fminf(u2, 0.0f); \
            bool g2   = u2 < 0.0f; \
            bool att  = sx2 < r * Y; \
            float af  = att ? a_af : a_sf; \
            float as2 = att ? a_as : a_ss; \
            float jYx = jFx + jSx, jYy = jFy + jSy; \
            float jtx = g2 ? nq * jYx : 0.0f; \
            float jty = g2 ? nq * jYy : 0.0f; \
            jFx = fmaf(af,  jFx - jtx, jtx); \
            jFy = fmaf(af,  jFy - jty, jty); \
            jSx = fmaf(as2, jSx - jtx, jtx); \
            jSy = fmaf(as2, jSy - jty, jty); \
            EF  = fmaf(af,  EF - t2, t2); \
            ES  = fmaf(as2, ES - t2, t2); \
            Y   = EF + ES; }
            SSL_STEP_J(xv.x)
            SSL_STEP_J(xv.y)
            SSL_STEP_J(xv.z)
            SSL_STEP_J(xv.w)
#undef SSL_STEP_J
        }
    }
    J = make_float4(jFx, jFy, jSx, jSy);
}

// Pass 1: diagonal chunk maps at K ES-nodes, SUB snapshots per node.
// tid: k in low 4 bits (K=16) -> 4 bc-groups per wave, broadcast x loads.
__global__ __launch_bounds__(256) void ssl_map(
        const float* __restrict__ x, float2* __restrict__ mp,
        const float* cth, const float* rl, const float* fbl,
        const float* uaf, const float* uas, const float* usf, const float* uss,
        int B)
{
    int tid = blockIdx.x * 256 + threadIdx.x;
    int k  = tid & (K - 1);
    int bc = tid >> 4;                       // b*NCM + c
    if (bc >= B * NCM) return;
    int c  = bc & (NCM - 1);
    int b  = bc >> 6;                        // NCM = 64

    SslParams P = ssl_params(cth, rl, fbl, uaf, uas, usf, uss);
    float v0s = -STEP_ES * (float)k;
    float EF = v0s, ES = v0s;
    const float4* xr = reinterpret_cast<const float4*>(x + (size_t)b * T_LEN);
    const int v0 = (c * CM) >> 2;
    #pragma unroll
    for (int q = 0; q < SUB; ++q) {
        run_chunk<false>(xr, nullptr, v0 + q * (SL >> 2), v0 + (q + 1) * (SL >> 2), EF, ES, P);
        mp[((size_t)bc * SUB + q) * K + k] = make_float2(EF, ES);
    }
}

// Pass 2: serial interp compose -> initial guesses at all NC fine boundaries.
__global__ __launch_bounds__(64) void ssl_compose0(
        const float2* __restrict__ mp, float2* __restrict__ bnd0, int B)
{
    int b = blockIdx.x * 64 + threadIdx.x;
    if (b >= B) return;
    float EF = 0.0f, ES = 0.0f;
    for (int c = 0; c < NCM; ++c) {
        int bc = b * NCM + c;
        bnd0[b * NC + SUB * c] = make_float2(EF, ES);
        float t = -ES * INV_STEP;
        int idx = (int)t;
        idx = idx < 0 ? 0 : (idx > K - 2 ? K - 2 : idx);
        float u = t - (float)idx;
        const float2* m = &mp[(size_t)bc * SUB * K];
        #pragma unroll
        for (int q = 0; q < SUB; ++q) {
            float2 a0 = m[q * K + idx], a1 = m[q * K + idx + 1];
            float gx = a0.x + (a1.x - a0.x) * u;
            float gy = a0.y + (a1.y - a0.y) * u;
            if (q < SUB - 1) bnd0[b * NC + SUB * c + 1 + q] = make_float2(gx, gy);
            else { EF = gx; ES = gy; }
        }
    }
}

// Jac pass: parallel exact runs from guesses; emit affine form (J, g = F - J*s0).
__global__ __launch_bounds__(64) void ssl_jac(
        const float* __restrict__ x,
        const float2* __restrict__ bndin,
        float4* __restrict__ Jv, float2* __restrict__ gv,
        const float* cth, const float* rl, const float* fbl,
        const float* uaf, const float* uas, const float* usf, const float* uss,
        int B)
{
    int tid = blockIdx.x * 64 + threadIdx.x;
    int b = tid % B;
    int c = tid / B;
    if (c >= NC) return;

    SslParams P = ssl_params(cth, rl, fbl, uaf, uas, usf, uss);
    float2 s0 = bndin[b * NC + c];
    float EF = s0.x, ES = s0.y;
    float4 J;
    const float4* xr = reinterpret_cast<const float4*>(x + (size_t)b * T_LEN);
    run_chunk_jac(xr, (c * CF) >> 2, ((c + 1) * CF) >> 2, EF, ES, J, P);
    Jv[b * NC + c] = J;
    gv[b * NC + c] = make_float2(EF - (J.x * s0.x + J.y * s0.y),
                                 ES - (J.z * s0.x + J.w * s0.y));
}

// Affine compose: s_{c+1} = J_c*s_c + g_c. Statically-addressed loads pipeline.
__global__ __launch_bounds__(64) void ssl_compose1(
        const float4* __restrict__ Jv, const float2* __restrict__ gv,
        float2* __restrict__ bndout, int B)
{
    int b = blockIdx.x * 64 + threadIdx.x;
    if (b >= B) return;
    const float4* Jr = Jv + (size_t)b * NC;
    const float2* gr = gv + (size_t)b * NC;
    float2* br = bndout + (size_t)b * NC;
    float sx = 0.0f, sy = 0.0f;
    #pragma unroll 8
    for (int c = 0; c < NC; ++c) {
        br[c] = make_float2(sx, sy);
        float4 J = Jr[c];
        float2 g = gr[c];
        float nx = g.x + J.x * sx + J.y * sy;
        float ny = g.y + J.z * sx + J.w * sy;
        sx = nx; sy = ny;
    }
}

// Out pass: rerun each fine chunk from its corrected boundary state, store y.
__global__ __launch_bounds__(64) void ssl_out(
        const float* __restrict__ x, float* __restrict__ out,
        const float2* __restrict__ bnd,
        const float* cth, const float* rl, const float* fbl,
        const float* uaf, const float* uas, const float* usf, const float* uss,
        int B)
{
    int tid = blockIdx.x * 64 + threadIdx.x;
    int b = tid % B;
    int c = tid / B;
    if (c >= NC) return;

    SslParams P = ssl_params(cth, rl, fbl, uaf, uas, usf, uss);
    float2 s = bnd[b * NC + c];
    float EF = s.x, ES = s.y;
    const float4* xr = reinterpret_cast<const float4*>(x + (size_t)b * T_LEN);
    float4* yr       = reinterpret_cast<float4*>(out + (size_t)b * T_LEN);
    run_chunk<true>(xr, yr, (c * CF) >> 2, ((c + 1) * CF) >> 2, EF, ES, P);
}

extern "C" void kernel_launch(void* const* d_in, const int* in_sizes, int n_in,
                              void* d_out, int out_size, void* d_ws, size_t ws_size,
                              hipStream_t stream) {
    const float* x = (const float*)d_in[0];
    const int B = in_sizes[0] / T_LEN;   // 128
    const int NCt = B * NC;              // 32768 fine chunks total

    // ws layout: Jv (float4, 16B-aligned first), then float2 arrays.
    float4* Jv   = (float4*)d_ws;                          // [B][NC]   (reused)
    float2* mp   = (float2*)(Jv + (size_t)NCt);            // [B*NCM][SUB][K]
    float2* bnd0 = mp + (size_t)B * NCM * SUB * K;         // [B][NC]
    float2* gv   = bnd0 + (size_t)NCt;                     // [B][NC]   (reused)
    float2* bnd1 = gv + (size_t)NCt;                       // [B][NC]
    float2* bnd2 = bnd1 + (size_t)NCt;                     // [B][NC]

    const float* cth = (const float*)d_in[1];
    const float* rl  = (const float*)d_in[2];
    const float* fbl = (const float*)d_in[3];
    const float* uaf = (const float*)d_in[4];
    const float* uas = (const float*)d_in[5];
    const float* usf = (const float*)d_in[6];
    const float* uss = (const float*)d_in[7];

    int map_threads = B * NCM * K;       // 131072
    ssl_map<<<(map_threads + 255) / 256, 256, 0, stream>>>(
        x, mp, cth, rl, fbl, uaf, uas, usf, uss, B);

    ssl_compose0<<<(B + 63) / 64, 64, 0, stream>>>(mp, bnd0, B);

    // Newton iteration 1
    ssl_jac<<<(NCt + 63) / 64, 64, 0, stream>>>(
        x, bnd0, Jv, gv, cth, rl, fbl, uaf, uas, usf, uss, B);
    ssl_compose1<<<(B + 63) / 64, 64, 0, stream>>>(Jv, gv, bnd1, B);

    // Newton iteration 2 (reuses Jv/gv)
    ssl_jac<<<(NCt + 63) / 64, 64, 0, stream>>>(
        x, bnd1, Jv, gv, cth, rl, fbl, uaf, uas, usf, uss, B);
    ssl_compose1<<<(B + 63) / 64, 64, 0, stream>>>(Jv, gv, bnd2, B);

    ssl_out<<<(NCt + 63) / 64, 64, 0, stream>>>(
        x, (float*)d_out, bnd2, cth, rl, fbl, uaf, uas, usf, uss, B);
}